// Round 10
// baseline (43.356 us; speedup 1.0000x reference)
//
#include <hip/hip_runtime.h>

typedef __attribute__((ext_vector_type(4))) float f32x4;
typedef __attribute__((ext_vector_type(8))) short bf16x8;

#define NP 4096
#define IB 16              // peds per block
#define GP 520             // grid LDS row pitch in shorts (1040 B: b128-aligned, 2-way)

__device__ __forceinline__ unsigned short f2bf(float f) {
  unsigned int u = __float_as_uint(f);
  u = u + 0x7FFFu + ((u >> 16) & 1u);   // round-to-nearest-even
  return (unsigned short)(u >> 16);
}

// ---------------- W fp32 -> bf16 convert (once) ----------------
__global__ __launch_bounds__(256) void wconv_kernel(
    const float* __restrict__ W, unsigned short* __restrict__ Wb) {
  int i = (blockIdx.x * 256 + threadIdx.x) * 8;
  float4 w0 = *(const float4*)&W[i];
  float4 w1 = *(const float4*)&W[i + 4];
  bf16x8 bv;
  bv[0] = (short)f2bf(w0.x); bv[1] = (short)f2bf(w0.y);
  bv[2] = (short)f2bf(w0.z); bv[3] = (short)f2bf(w0.w);
  bv[4] = (short)f2bf(w1.x); bv[5] = (short)f2bf(w1.y);
  bv[6] = (short)f2bf(w1.z); bv[7] = (short)f2bf(w1.w);
  *(bf16x8*)&Wb[i] = bv;
}

// ---------------- fused pool + GEMM ----------------
// Block = 16 peds, 512 threads (8 waves). Phase 1 (pool): tx=ped (tid&15),
// ty=j-slot (tid>>4, 32 slots, 128 js each). Per in-range pair ONE u64 LDS
// atomic packing (qx+2^14)<<38 | (qy+2^14)<<12 | 1, scale 2^-11 (order-
// independent integer accumulation; same numerics as R5: absmax 0.0156).
// Self-pair lands in cell 136 with qx=qy=0, cnt 1; compensated at decode.
// Phase 2: decode acc -> bf16 grid[16][520] in LDS (mean per cell).
// Phase 3: out[16x256] = relu(grid[16x512] @ Wb^T + b) via MFMA 16x16x32;
// wave w owns out cols [32w,32w+32); A from LDS, B streamed from L2.
__global__ __launch_bounds__(512) void fused_kernel(
    const float2* __restrict__ pos, const float2* __restrict__ past,
    const unsigned short* __restrict__ Wb, const float* __restrict__ bias,
    float* __restrict__ out) {
  __shared__ unsigned long long acc[IB][256];    // 32 KB
  __shared__ unsigned short grid[IB][GP];        // 16.6 KB
  const int tid = threadIdx.x;
  const int tx = tid & 15;
  const int ty = tid >> 4;          // 0..31
  const int ibase = blockIdx.x * IB;
  const int i = ibase + tx;

  for (int idx = tid; idx < IB * 256; idx += 512)
    acc[idx >> 8][idx & 255] = 0ull;
  __syncthreads();

  // ---- phase 1: pool ----
  const float2 pi = pos[i];
  const float2 qi = past[i];
  const float vix = pi.x - qi.x;
  const float viy = pi.y - qi.y;
  unsigned long long* accp = acc[tx];
  const float inv06 = 1.0f / 0.6f;

  auto process = [&](float2 pj, float2 qj) {
    float rx = pj.x - pi.x;
    float ry = pj.y - pi.y;
    float ax = __builtin_fmaf(rx, inv06, 8.0f);
    float ay = __builtin_fmaf(ry, inv06, 8.0f);
    bool unc = (fabsf(ax - rintf(ax)) < 1e-4f) |
               (fabsf(ay - rintf(ay)) < 1e-4f);
    float fx, fy;
    if (__any(unc)) {
      // exact IEEE fp32 division path to match numpy floor(rel/0.6 + 8)
      fx = floorf(rx / 0.6f + 8.0f);
      fy = floorf(ry / 0.6f + 8.0f);
    } else {
      fx = floorf(ax);
      fy = floorf(ay);
    }
    int ix = (int)fx;
    int iy = (int)fy;
    if (((unsigned)ix < 16u) & ((unsigned)iy < 16u)) {
      float rvx = (pj.x - qj.x) - vix;
      float rvy = (pj.y - qj.y) - viy;
      unsigned int qx = (unsigned int)((int)rintf(rvx * 2048.0f) + 16384);
      unsigned int qy = (unsigned int)((int)rintf(rvy * 2048.0f) + 16384);
      unsigned long long p = ((unsigned long long)qx << 38) |
                             ((unsigned long long)qy << 12) | 1ull;
      atomicAdd(&accp[(ix << 4) + iy], p);
    }
  };

  for (int jo = 0; jo < NP; jo += 128) {
    int j0 = jo + ty;
    float2 p0 = pos[j0];       float2 q0 = past[j0];
    float2 p1 = pos[j0 + 32];  float2 q1 = past[j0 + 32];
    float2 p2 = pos[j0 + 64];  float2 q2 = past[j0 + 64];
    float2 p3 = pos[j0 + 96];  float2 q3 = past[j0 + 96];
    process(p0, q0);
    process(p1, q1);
    process(p2, q2);
    process(p3, q3);
  }
  __syncthreads();

  // ---- phase 2: decode + normalize -> bf16 grid in LDS ----
#pragma unroll
  for (int idx = tid; idx < IB * 256; idx += 512) {
    const int ped = idx >> 8;
    const int cell = idx & 255;
    unsigned long long raw = acc[ped][cell];
    unsigned int cnt = (unsigned int)(raw & 0xFFFull);
    int sxq = (int)((unsigned int)(raw >> 38)) - (int)(cnt << 14);
    int syq = (int)((unsigned int)((raw >> 12) & 0x3FFFFFFull)) - (int)(cnt << 14);
    float cn = (float)cnt - ((cell == 136) ? 1.0f : 0.0f);
    float d = fmaxf(cn, 1.0f);
    float sx = (float)sxq * (1.0f / 2048.0f);
    float sy = (float)syq * (1.0f / 2048.0f);
    unsigned int packed =
        ((unsigned int)f2bf(sy / d) << 16) | (unsigned int)f2bf(sx / d);
    *(unsigned int*)&grid[ped][cell * 2] = packed;
  }
  __syncthreads();

  // ---- phase 3: MFMA gemm: out[16][256] = relu(grid @ Wb^T + bias) ----
  const int lane = tid & 63;
  const int w = tid >> 6;           // 0..7 -> n-block [32w, 32w+32)
  const int lrow = lane & 15;
  const int lk8 = (lane >> 4) * 8;
  const int nb = w * 32;

  f32x4 o0 = {0.f, 0.f, 0.f, 0.f};
  f32x4 o1 = {0.f, 0.f, 0.f, 0.f};

  for (int ks = 0; ks < 16; ks += 4) {
    bf16x8 av[4], b0[4], b1[4];
#pragma unroll
    for (int u = 0; u < 4; ++u) {
      const int k0 = (ks + u) * 32 + lk8;
      av[u] = *(const bf16x8*)&grid[lrow][k0];
      b0[u] = *(const bf16x8*)&Wb[(size_t)(nb + lrow) * 512 + k0];
      b1[u] = *(const bf16x8*)&Wb[(size_t)(nb + 16 + lrow) * 512 + k0];
    }
#pragma unroll
    for (int u = 0; u < 4; ++u) {
      o0 = __builtin_amdgcn_mfma_f32_16x16x32_bf16(av[u], b0[u], o0, 0, 0, 0);
      o1 = __builtin_amdgcn_mfma_f32_16x16x32_bf16(av[u], b1[u], o1, 0, 0, 0);
    }
  }

  // D layout: row(ped) = (lane>>4)*4 + q, col = lane&15
  const int rq = (lane >> 4) * 4;
  const float bv0 = bias[nb + lrow];
  const float bv1 = bias[nb + 16 + lrow];
#pragma unroll
  for (int q = 0; q < 4; ++q) {
    const size_t row = (size_t)(ibase + rq + q) * 256;
    out[row + nb + lrow] = fmaxf(o0[q] + bv0, 0.0f);
    out[row + nb + 16 + lrow] = fmaxf(o1[q] + bv1, 0.0f);
  }
}

extern "C" void kernel_launch(void* const* d_in, const int* in_sizes, int n_in,
                              void* d_out, int out_size, void* d_ws, size_t ws_size,
                              hipStream_t stream) {
  // inputs: 0=h (unused), 1=positions, 2=past_positions, 3=W_emb, 4=b_emb
  const float2* pos = (const float2*)d_in[1];
  const float2* past = (const float2*)d_in[2];
  const float* W = (const float*)d_in[3];
  const float* bias = (const float*)d_in[4];
  float* out = (float*)d_out;

  unsigned short* Wb = (unsigned short*)d_ws;  // 256 KB bf16 W

  wconv_kernel<<<(256 * 512) / (256 * 8), 256, 0, stream>>>(W, Wb);
  fused_kernel<<<NP / IB, 512, 0, stream>>>(pos, past, Wb, bias, out);
}

// Round 11
// 35.987 us; speedup vs baseline: 1.2048x; 1.2048x over previous
//
#include <hip/hip_runtime.h>

typedef __attribute__((ext_vector_type(4))) float f32x4;
typedef __attribute__((ext_vector_type(8))) short bf16x8;

#define NP 4096

__device__ __forceinline__ unsigned short f2bf(float f) {
  unsigned int u = __float_as_uint(f);
  u = u + 0x7FFFu + ((u >> 16) & 1u);   // round-to-nearest-even
  return (unsigned short)(u >> 16);
}

// ---------------- pool: lane-owns-j, 4 peds amortized ----------------
// 1024 blocks x 256 threads (8 blocks/CU -> 32 waves/CU). Each lane owns
// j = jo + tid, loads pos/past[j] ONCE, computes v_j ONCE, then serves the
// block's 4 peds: bin (fma approx + exact-IEEE-div fallback when any lane
// near a cell boundary -> bit-exact vs numpy) + ONE u64 LDS atomic per hit
// packing (qx+2^14)<<38 | (qy+2^14)<<12 | 1, scale 2^-11 (order-independent).
// Self-pair lands in cell 136 with qx=qy=0, cnt 1; compensated at decode.
// Threads 0..15 also convert 128 W elements fp32->bf16 (1024 x 128 = 256*512).
__global__ __launch_bounds__(256, 8) void pool_kernel(
    const float2* __restrict__ pos, const float2* __restrict__ past,
    const float* __restrict__ W, unsigned short* __restrict__ Wb,
    unsigned short* __restrict__ gridws) {
  __shared__ unsigned long long acc[4][256];   // 8 KB
  const int tid = threadIdx.x;
  const int ibase = blockIdx.x * 4;

  if (tid < 16) {
    int idx = blockIdx.x * 128 + tid * 8;
    float4 w0 = *(const float4*)&W[idx];
    float4 w1 = *(const float4*)&W[idx + 4];
    bf16x8 bv;
    bv[0] = (short)f2bf(w0.x); bv[1] = (short)f2bf(w0.y);
    bv[2] = (short)f2bf(w0.z); bv[3] = (short)f2bf(w0.w);
    bv[4] = (short)f2bf(w1.x); bv[5] = (short)f2bf(w1.y);
    bv[6] = (short)f2bf(w1.z); bv[7] = (short)f2bf(w1.w);
    *(bf16x8*)&Wb[idx] = bv;
  }

  for (int idx = tid; idx < 1024; idx += 256)
    ((unsigned long long*)acc)[idx] = 0ull;
  __syncthreads();

  float2 pip[4];
  float vix[4], viy[4];
#pragma unroll
  for (int t = 0; t < 4; ++t) {
    float2 p = pos[ibase + t];
    float2 q = past[ibase + t];
    pip[t] = p;
    vix[t] = p.x - q.x;
    viy[t] = p.y - q.y;
  }
  const float inv06 = 1.0f / 0.6f;

  for (int jo = 0; jo < NP; jo += 256) {
    const int j = jo + tid;
    const float2 pj = pos[j];
    const float2 qj = past[j];
    const float vjx = pj.x - qj.x;
    const float vjy = pj.y - qj.y;
#pragma unroll
    for (int t = 0; t < 4; ++t) {
      float rx = pj.x - pip[t].x;
      float ry = pj.y - pip[t].y;
      float ax = __builtin_fmaf(rx, inv06, 8.0f);
      float ay = __builtin_fmaf(ry, inv06, 8.0f);
      bool unc = (fabsf(ax - rintf(ax)) < 1e-4f) |
                 (fabsf(ay - rintf(ay)) < 1e-4f);
      float fx, fy;
      if (__any(unc)) {
        // exact IEEE fp32 division path to match numpy floor(rel/0.6 + 8)
        fx = floorf(rx / 0.6f + 8.0f);
        fy = floorf(ry / 0.6f + 8.0f);
      } else {
        fx = floorf(ax);
        fy = floorf(ay);
      }
      int ix = (int)fx;
      int iy = (int)fy;
      if (((unsigned)ix < 16u) & ((unsigned)iy < 16u)) {
        unsigned int qx = (unsigned int)((int)rintf((vjx - vix[t]) * 2048.0f) + 16384);
        unsigned int qy = (unsigned int)((int)rintf((vjy - viy[t]) * 2048.0f) + 16384);
        unsigned long long p = ((unsigned long long)qx << 38) |
                               ((unsigned long long)qy << 12) | 1ull;
        atomicAdd(&acc[t][(ix << 4) + iy], p);
      }
    }
  }
  __syncthreads();

  // epilogue: decode u64, normalize (mean per cell), store bf16 [NP][512]
  const int cell = tid;  // 0..255
  const float selfc = (cell == 136) ? 1.0f : 0.0f;
#pragma unroll
  for (int t = 0; t < 4; ++t) {
    unsigned long long raw = acc[t][cell];
    unsigned int cnt = (unsigned int)(raw & 0xFFFull);
    int sxq = (int)((unsigned int)(raw >> 38)) - (int)(cnt << 14);
    int syq = (int)((unsigned int)((raw >> 12) & 0x3FFFFFFull)) - (int)(cnt << 14);
    float cn = (float)cnt - selfc;
    float d = fmaxf(cn, 1.0f);
    float sx = (float)sxq * (1.0f / 2048.0f);
    float sy = (float)syq * (1.0f / 2048.0f);
    unsigned int packed =
        ((unsigned int)f2bf(sy / d) << 16) | (unsigned int)f2bf(sx / d);
    *(unsigned int*)&gridws[(size_t)(ibase + t) * 512 + cell * 2] = packed;
  }
}

// ---------------- GEMM: split-K, occupancy-sized ----------------
// C[4096][256] = relu(A[4096][512](bf16) @ Wb[256][512]^T + b), fp32 out.
// Block = 16x64 output tile, 256 threads / 4 waves; wave w owns K-slice
// [128w, 128w+128) = 4 MFMA k-steps (2-deep load pipeline, no k-barriers).
// Partials to red[4][64][20] (20.5 KB -> 8 blocks/CU; 16B-aligned f32x4
// writes; reduce reads conflict-free: 20*col % 32 is 2-way max). One barrier,
// then 256 threads: float4 partial sums + bias + relu + coalesced stores.
__global__ __launch_bounds__(256) void gemm_kernel(
    const unsigned short* __restrict__ A, const unsigned short* __restrict__ Wb,
    const float* __restrict__ bias, float* __restrict__ out) {
  __shared__ float red[4][64][20];
  const int tid = threadIdx.x;
  const int lane = tid & 63;
  const int w = tid >> 6;            // 0..3 K-slice
  const int mbase = blockIdx.x * 16;
  const int nbase = blockIdx.y * 64;
  const int lrow = lane & 15;
  const int lk8 = (lane >> 4) * 8;

  f32x4 acc[4] = {};
#pragma unroll
  for (int ksp = 0; ksp < 4; ksp += 2) {
    bf16x8 a[2], b[2][4];
#pragma unroll
    for (int u = 0; u < 2; ++u) {
      const int k0 = w * 128 + (ksp + u) * 32 + lk8;
      a[u] = *(const bf16x8*)&A[(size_t)(mbase + lrow) * 512 + k0];
#pragma unroll
      for (int nf = 0; nf < 4; ++nf)
        b[u][nf] = *(const bf16x8*)&Wb[(size_t)(nbase + nf * 16 + lrow) * 512 + k0];
    }
#pragma unroll
    for (int u = 0; u < 2; ++u)
#pragma unroll
      for (int nf = 0; nf < 4; ++nf)
        acc[nf] = __builtin_amdgcn_mfma_f32_16x16x32_bf16(
            a[u], b[u][nf], acc[nf], 0, 0, 0);
  }

  // D layout: row(m) = (lane>>4)*4 + q, col(n) = nf*16 + (lane&15)
  const int rq = (lane >> 4) * 4;
#pragma unroll
  for (int nf = 0; nf < 4; ++nf)
    *(f32x4*)&red[w][nf * 16 + lrow][rq] = acc[nf];
  __syncthreads();

  const int col = tid & 63;
  const int mq = (tid >> 6) * 4;
  f32x4 s = {};
#pragma unroll
  for (int w2 = 0; w2 < 4; ++w2) {
    f32x4 r = *(const f32x4*)&red[w2][col][mq];
    s += r;
  }
  const float bv = bias[nbase + col];
#pragma unroll
  for (int q = 0; q < 4; ++q)
    out[(size_t)(mbase + mq + q) * 256 + nbase + col] = fmaxf(s[q] + bv, 0.0f);
}

extern "C" void kernel_launch(void* const* d_in, const int* in_sizes, int n_in,
                              void* d_out, int out_size, void* d_ws, size_t ws_size,
                              hipStream_t stream) {
  // inputs: 0=h (unused), 1=positions, 2=past_positions, 3=W_emb, 4=b_emb
  const float2* pos = (const float2*)d_in[1];
  const float2* past = (const float2*)d_in[2];
  const float* W = (const float*)d_in[3];
  const float* bias = (const float*)d_in[4];
  float* out = (float*)d_out;

  unsigned short* gridws = (unsigned short*)d_ws;                         // 4 MB
  unsigned short* Wb = (unsigned short*)((char*)d_ws + 4 * 1024 * 1024);  // 256 KB

  pool_kernel<<<NP / 4, 256, 0, stream>>>(pos, past, W, Wb, gridws);
  dim3 g(NP / 16, 256 / 64);
  gemm_kernel<<<g, 256, 0, stream>>>(gridws, Wb, bias, out);
}